// Round 1
// baseline (109.187 us; speedup 1.0000x reference)
//
#include <hip/hip_runtime.h>

#define M_ 256
#define K_ 8192
#define N_ 8192

typedef int v4i __attribute__((ext_vector_type(4)));
typedef int v16i __attribute__((ext_vector_type(16)));

// ---------------- kernel 1: per-token int8 quantization ----------------
// one block per row (m), 256 threads, each handles 32 floats (8x float4)
__global__ __launch_bounds__(256) void awq_quant(const float* __restrict__ x,
                                                 signed char* __restrict__ xq,
                                                 float* __restrict__ scales) {
    const int m = blockIdx.x;
    const int t = threadIdx.x;
    const float4* xrow = (const float4*)(x + (size_t)m * K_);
    float4 v[8];
    float mx = 0.0f;
#pragma unroll
    for (int j = 0; j < 8; ++j) {
        v[j] = xrow[j * 256 + t];
        mx = fmaxf(mx, fmaxf(fmaxf(fabsf(v[j].x), fabsf(v[j].y)),
                             fmaxf(fabsf(v[j].z), fabsf(v[j].w))));
    }
#pragma unroll
    for (int off = 32; off > 0; off >>= 1) mx = fmaxf(mx, __shfl_xor(mx, off, 64));
    __shared__ float red[4];
    if ((t & 63) == 0) red[t >> 6] = mx;
    __syncthreads();
    mx = fmaxf(fmaxf(red[0], red[1]), fmaxf(red[2], red[3]));
    // exactly match reference: max(max_abs/127.0, 1e-8), true fp32 division
    const float scale = fmaxf(mx / 127.0f, 1e-8f);

    int* xqd = (int*)(xq + (size_t)m * K_);
#pragma unroll
    for (int j = 0; j < 8; ++j) {
        // rintf == round-half-to-even == jnp.round
        const int q0 = (int)fminf(fmaxf(rintf(v[j].x / scale), -127.0f), 127.0f);
        const int q1 = (int)fminf(fmaxf(rintf(v[j].y / scale), -127.0f), 127.0f);
        const int q2 = (int)fminf(fmaxf(rintf(v[j].z / scale), -127.0f), 127.0f);
        const int q3 = (int)fminf(fmaxf(rintf(v[j].w / scale), -127.0f), 127.0f);
        xqd[j * 256 + t] = (q0 & 255) | ((q1 & 255) << 8) | ((q2 & 255) << 16) | ((q3 & 255) << 24);
    }
    if (t == 0) scales[m] = scale;
}

// ---------------- kernel 2: int8 GEMM + dequant epilogue ----------------
// grid = N/32 = 256 blocks (1/CU). block = 512 thr = 8 waves.
// Each block: out[0:256][n0:n0+32]. Wave w owns m-tile rows [32w, 32w+32).
// qw staged per 256-k super-chunk: reg load -> byte pack+4x4 transpose (v_perm)
// -> LDS [n][k] tile (row pad 272B), double buffered, 1 barrier/superchunk.
// A (xq) fragments load straight from global (L2-resident, k-contiguous 16B).

__device__ __forceinline__ void stage_b(char* btn, int bwo,
                                        const int4& w0, const int4& w1,
                                        const int4& w2, const int4& w3) {
    const int* p0 = (const int*)&w0;
    const int* p1 = (const int*)&w1;
    const int* p2 = (const int*)&w2;
    const int* p3 = (const int*)&w3;
#pragma unroll
    for (int j = 0; j < 4; ++j) {
        // gather low byte (int8 value) of the 4 k-rows for column j
        const unsigned u = __builtin_amdgcn_perm((unsigned)p1[j], (unsigned)p0[j], 0x00000400u); // [r0,r1,-,-]
        const unsigned w = __builtin_amdgcn_perm((unsigned)p3[j], (unsigned)p2[j], 0x00000400u); // [r2,r3,-,-]
        const unsigned o = __builtin_amdgcn_perm(w, u, 0x05040100u);                             // [r0,r1,r2,r3]
        *(unsigned*)(btn + bwo + j * 272) = o;
    }
}

__global__ __launch_bounds__(512) void awq_gemm(const signed char* __restrict__ xq,
                                                const float* __restrict__ scales,
                                                const int* __restrict__ qw,
                                                const float* __restrict__ wscale,
                                                const float* __restrict__ bias,
                                                float* __restrict__ out) {
    __shared__ __align__(16) char btile[2][32 * 272];   // [buf][n=32][kpad=272B]
    const int t = threadIdx.x;
    const int lane = t & 63;
    const int wave = t >> 6;               // m-tile index, 0..7
    const int n0 = blockIdx.x * 32;

    // B staging mapping: thread covers 4 k-rows x 4 n-cols of the super-chunk
    const int sa = t & 7;                  // n-group: cols n0 + 4*sa + j
    const int sr = t >> 3;                 // 0..63: k rows 4*sr + i
    const int* qbase = qw + (size_t)(4 * sr) * N_ + n0 + 4 * sa;

    // A fragment base: lane -> row (lane&31), k-halfgroup (lane>>5)*16
    const signed char* xqb = xq + (size_t)(wave * 32 + (lane & 31)) * K_ + (lane >> 5) * 16;

    const int bro = (lane & 31) * 272 + (lane >> 5) * 16;   // B frag read (+ks*32)
    const int bwo = (4 * sa) * 272 + 4 * sr;                // B stage write (+j*272)

    v16i acc = {};
    v4i aF[8];
    int4 w0, w1, w2, w3;

    // prologue: stage super-chunk 0, prefetch A frags for super 0
    {
        const int4* q = (const int4*)qbase;
        w0 = q[0]; w1 = q[N_ / 4]; w2 = q[2 * (N_ / 4)]; w3 = q[3 * (N_ / 4)];
    }
#pragma unroll
    for (int ks = 0; ks < 8; ++ks) aF[ks] = *(const v4i*)(xqb + ks * 32);
    stage_b(&btile[0][0], bwo, w0, w1, w2, w3);
    __syncthreads();

    for (int sc = 0; sc < 32; ++sc) {
        const int scn = (sc + 1 < 32) ? sc + 1 : 31;   // clamped prefetch target
        {   // issue next super-chunk qw loads early (consumed at stage_b below)
            const int4* q = (const int4*)(qbase + (size_t)scn * 256 * N_);
            w0 = q[0]; w1 = q[N_ / 4]; w2 = q[2 * (N_ / 4)]; w3 = q[3 * (N_ / 4)];
        }
        const char* btc = &btile[sc & 1][0];
#pragma unroll
        for (int ks = 0; ks < 8; ++ks) {
            const v4i bf = *(const v4i*)(btc + bro + ks * 32);
            acc = __builtin_amdgcn_mfma_i32_32x32x32_i8(aF[ks], bf, acc, 0, 0, 0);
            aF[ks] = *(const v4i*)(xqb + scn * 256 + ks * 32);  // refill for next super
        }
        stage_b(&btile[(sc + 1) & 1][0], bwo, w0, w1, w2, w3);
        __syncthreads();
    }

    // epilogue: dequant. C/D layout (verified): col=lane&31, row=(g&3)+8*(g>>2)+4*(lane>>5)
    const int n = n0 + (lane & 31);
    const float wn = wscale[n];
    const float bn = bias[n];
    const int mb = wave * 32 + 4 * (lane >> 5);
#pragma unroll
    for (int g = 0; g < 16; ++g) {
        const int m = mb + (g & 3) + 8 * (g >> 2);
        out[(size_t)m * N_ + n] = ((float)acc[g] * scales[m]) * wn + bn;
    }
}

extern "C" void kernel_launch(void* const* d_in, const int* in_sizes, int n_in,
                              void* d_out, int out_size, void* d_ws, size_t ws_size,
                              hipStream_t stream) {
    const float* x    = (const float*)d_in[0];
    const int*   qw   = (const int*)d_in[1];
    const float* wsc  = (const float*)d_in[2];
    const float* bias = (const float*)d_in[3];
    float* out = (float*)d_out;

    signed char* xqbuf  = (signed char*)d_ws;                     // 2 MB
    float*       scales = (float*)((char*)d_ws + (size_t)M_ * K_); // 1 KB

    awq_quant<<<M_, 256, 0, stream>>>(x, xqbuf, scales);
    awq_gemm<<<N_ / 32, 512, 0, stream>>>(xqbuf, scales, qw, wsc, bias, out);
}

// Round 2
// 92.844 us; speedup vs baseline: 1.1760x; 1.1760x over previous
//
#include <hip/hip_runtime.h>

#define M_ 256
#define K_ 8192
#define N_ 8192

typedef int v4i __attribute__((ext_vector_type(4)));
typedef int v16i __attribute__((ext_vector_type(16)));

// ---------------- kernel 1: per-token int8 quantization ----------------
__global__ __launch_bounds__(256) void awq_quant(const float* __restrict__ x,
                                                 signed char* __restrict__ xq,
                                                 float* __restrict__ scales) {
    const int m = blockIdx.x;
    const int t = threadIdx.x;
    const float4* xrow = (const float4*)(x + (size_t)m * K_);
    float4 v[8];
    float mx = 0.0f;
#pragma unroll
    for (int j = 0; j < 8; ++j) {
        v[j] = xrow[j * 256 + t];
        mx = fmaxf(mx, fmaxf(fmaxf(fabsf(v[j].x), fabsf(v[j].y)),
                             fmaxf(fabsf(v[j].z), fabsf(v[j].w))));
    }
#pragma unroll
    for (int off = 32; off > 0; off >>= 1) mx = fmaxf(mx, __shfl_xor(mx, off, 64));
    __shared__ float red[4];
    if ((t & 63) == 0) red[t >> 6] = mx;
    __syncthreads();
    mx = fmaxf(fmaxf(red[0], red[1]), fmaxf(red[2], red[3]));
    const float scale = fmaxf(mx / 127.0f, 1e-8f);

    int* xqd = (int*)(xq + (size_t)m * K_);
#pragma unroll
    for (int j = 0; j < 8; ++j) {
        const int q0 = (int)fminf(fmaxf(rintf(v[j].x / scale), -127.0f), 127.0f);
        const int q1 = (int)fminf(fmaxf(rintf(v[j].y / scale), -127.0f), 127.0f);
        const int q2 = (int)fminf(fmaxf(rintf(v[j].z / scale), -127.0f), 127.0f);
        const int q3 = (int)fminf(fmaxf(rintf(v[j].w / scale), -127.0f), 127.0f);
        xqd[j * 256 + t] = (q0 & 255) | ((q1 & 255) << 8) | ((q2 & 255) << 16) | ((q3 & 255) << 24);
    }
    if (t == 0) scales[m] = scale;
}

// ---------------- kernel 2: int8 GEMM + dequant epilogue ----------------
// grid = 256 blocks (1/CU), 512 thr = 8 waves, each wave one 32x32 m-tile.
// 2-stage pipeline with RAW barriers (no vmcnt drain): qw loads for chunk
// sc+2 issued at top of iter sc, consumed by stage_b one full iteration
// later. lgkmcnt(0)+s_barrier only -> one 32KB qw chunk/CU always in flight.

__device__ __forceinline__ void stage_b(char* btn, int bwo,
                                        const int4& w0, const int4& w1,
                                        const int4& w2, const int4& w3) {
    const int* p0 = (const int*)&w0;
    const int* p1 = (const int*)&w1;
    const int* p2 = (const int*)&w2;
    const int* p3 = (const int*)&w3;
#pragma unroll
    for (int j = 0; j < 4; ++j) {
        const unsigned u = __builtin_amdgcn_perm((unsigned)p1[j], (unsigned)p0[j], 0x00000400u);
        const unsigned w = __builtin_amdgcn_perm((unsigned)p3[j], (unsigned)p2[j], 0x00000400u);
        const unsigned o = __builtin_amdgcn_perm(w, u, 0x05040100u);
        *(unsigned*)(btn + bwo + j * 272) = o;
    }
}

__global__ __launch_bounds__(512) void awq_gemm(const signed char* __restrict__ xq,
                                                const float* __restrict__ scales,
                                                const int* __restrict__ qw,
                                                const float* __restrict__ wscale,
                                                const float* __restrict__ bias,
                                                float* __restrict__ out) {
    __shared__ __align__(16) char btile[2][32 * 272];
    const int t = threadIdx.x;
    const int lane = t & 63;
    const int wave = t >> 6;
    const int n0 = blockIdx.x * 32;

    const int sa = t & 7;                  // n-group
    const int sr = t >> 3;                 // k-row group
    const int* qbase = qw + (size_t)(4 * sr) * N_ + n0 + 4 * sa;

    const signed char* xqb = xq + (size_t)(wave * 32 + (lane & 31)) * K_ + (lane >> 5) * 16;

    const int bro = (lane & 31) * 272 + (lane >> 5) * 16;
    const int bwo = (4 * sa) * 272 + 4 * sr;

    v16i acc = {};
    v4i aF[8];
    int4 sA[4], sB[4];

    auto loadq = [&](int4* dst, int chunk) {
        const int4* q = (const int4*)(qbase + (size_t)chunk * 256 * N_);
        dst[0] = q[0];
        dst[1] = q[N_ / 4];
        dst[2] = q[2 * (N_ / 4)];
        dst[3] = q[3 * (N_ / 4)];
    };

    // prologue: S_A <- chunk0, S_B <- chunk1, aF <- chunk0, stage buf0
    loadq(sA, 0);
    loadq(sB, 1);
#pragma unroll
    for (int ks = 0; ks < 8; ++ks) aF[ks] = *(const v4i*)(xqb + ks * 32);
    stage_b(&btile[0][0], bwo, sA[0], sA[1], sA[2], sA[3]);
    asm volatile("s_waitcnt lgkmcnt(0)" ::: "memory");
    __builtin_amdgcn_s_barrier();
    __builtin_amdgcn_sched_barrier(0);

    for (int sc = 0; sc < 32; sc += 2) {
        {   // even: compute chunk sc (buf0); stage chunk sc+1 (sB) -> buf1; issue sc+2 -> sA
            const int c2 = (sc + 2 < 32) ? sc + 2 : 31;
            loadq(sA, c2);
            const int an = (sc + 1 < 32) ? sc + 1 : 31;
            const char* btc = &btile[0][0];
#pragma unroll
            for (int ks = 0; ks < 8; ++ks) {
                const v4i bf = *(const v4i*)(btc + bro + ks * 32);
                acc = __builtin_amdgcn_mfma_i32_32x32x32_i8(aF[ks], bf, acc, 0, 0, 0);
                aF[ks] = *(const v4i*)(xqb + an * 256 + ks * 32);
            }
            stage_b(&btile[1][0], bwo, sB[0], sB[1], sB[2], sB[3]);
            asm volatile("s_waitcnt lgkmcnt(0)" ::: "memory");
            __builtin_amdgcn_s_barrier();
            __builtin_amdgcn_sched_barrier(0);
        }
        {   // odd: compute chunk sc+1 (buf1); stage chunk sc+2 (sA) -> buf0; issue sc+3 -> sB
            const int c3 = (sc + 3 < 32) ? sc + 3 : 31;
            loadq(sB, c3);
            const int an = (sc + 2 < 32) ? sc + 2 : 31;
            const char* btc = &btile[1][0];
#pragma unroll
            for (int ks = 0; ks < 8; ++ks) {
                const v4i bf = *(const v4i*)(btc + bro + ks * 32);
                acc = __builtin_amdgcn_mfma_i32_32x32x32_i8(aF[ks], bf, acc, 0, 0, 0);
                aF[ks] = *(const v4i*)(xqb + an * 256 + ks * 32);
            }
            stage_b(&btile[0][0], bwo, sA[0], sA[1], sA[2], sA[3]);
            asm volatile("s_waitcnt lgkmcnt(0)" ::: "memory");
            __builtin_amdgcn_s_barrier();
            __builtin_amdgcn_sched_barrier(0);
        }
    }

    // epilogue: dequant. C/D layout: col=lane&31, row=(g&3)+8*(g>>2)+4*(lane>>5)
    const int n = n0 + (lane & 31);
    const float wn = wscale[n];
    const float bn = bias[n];
    const int mb = wave * 32 + 4 * (lane >> 5);
#pragma unroll
    for (int g = 0; g < 16; ++g) {
        const int m = mb + (g & 3) + 8 * (g >> 2);
        out[(size_t)m * N_ + n] = ((float)acc[g] * scales[m]) * wn + bn;
    }
}

extern "C" void kernel_launch(void* const* d_in, const int* in_sizes, int n_in,
                              void* d_out, int out_size, void* d_ws, size_t ws_size,
                              hipStream_t stream) {
    const float* x    = (const float*)d_in[0];
    const int*   qw   = (const int*)d_in[1];
    const float* wsc  = (const float*)d_in[2];
    const float* bias = (const float*)d_in[3];
    float* out = (float*)d_out;

    signed char* xqbuf  = (signed char*)d_ws;
    float*       scales = (float*)((char*)d_ws + (size_t)M_ * K_);

    awq_quant<<<M_, 256, 0, stream>>>(x, xqbuf, scales);
    awq_gemm<<<N_ / 32, 512, 0, stream>>>(xqbuf, scales, qw, wsc, bias, out);
}

// Round 4
// 66.123 us; speedup vs baseline: 1.6513x; 1.4041x over previous
//
#include <hip/hip_runtime.h>

#define M_ 256
#define K_ 8192
#define N_ 8192

typedef int v4i __attribute__((ext_vector_type(4)));
typedef int v16i __attribute__((ext_vector_type(16)));

// ---------------- kernel 1: per-token int8 quantization ----------------
// Writes xq in MFMA-A-fragment-tiled layout so the GEMM's A loads are
// perfectly coalesced. Bijective byte map (2 MB total):
//   (m,k) -> addr = (mt<<18) + (chunk<<13) + (ks<<10) + (lane<<4) + b
//   mt=m>>5, chunk=k>>8, ks=(k>>5)&7, lane=(m&31)+32*((k>>4)&1), b=k&15
__global__ __launch_bounds__(256) void awq_quant(const float* __restrict__ x,
                                                 signed char* __restrict__ xqt,
                                                 float* __restrict__ scales) {
    const int m = blockIdx.x;
    const int t = threadIdx.x;
    const float4* xrow = (const float4*)(x + (size_t)m * K_);
    float4 v[8];
    float mx = 0.0f;
#pragma unroll
    for (int j = 0; j < 8; ++j) {
        v[j] = xrow[j * 256 + t];
        mx = fmaxf(mx, fmaxf(fmaxf(fabsf(v[j].x), fabsf(v[j].y)),
                             fmaxf(fabsf(v[j].z), fabsf(v[j].w))));
    }
#pragma unroll
    for (int off = 32; off > 0; off >>= 1) mx = fmaxf(mx, __shfl_xor(mx, off, 64));
    __shared__ float red[4];
    if ((t & 63) == 0) red[t >> 6] = mx;
    __syncthreads();
    mx = fmaxf(fmaxf(red[0], red[1]), fmaxf(red[2], red[3]));
    const float scale = fmaxf(mx / 127.0f, 1e-8f);

    char* base = (char*)xqt + ((size_t)(m >> 5) << 18);
    const int ml = m & 31;
#pragma unroll
    for (int j = 0; j < 8; ++j) {
        const int q0 = (int)fminf(fmaxf(rintf(v[j].x / scale), -127.0f), 127.0f);
        const int q1 = (int)fminf(fmaxf(rintf(v[j].y / scale), -127.0f), 127.0f);
        const int q2 = (int)fminf(fmaxf(rintf(v[j].z / scale), -127.0f), 127.0f);
        const int q3 = (int)fminf(fmaxf(rintf(v[j].w / scale), -127.0f), 127.0f);
        const int packed = (q0 & 255) | ((q1 & 255) << 8) | ((q2 & 255) << 16) | ((q3 & 255) << 24);
        const int k0 = 4 * (j * 256 + t);
        const int addr = ((k0 >> 8) << 13) + (((k0 >> 5) & 7) << 10) +
                         ((ml + (((k0 >> 4) & 1) << 5)) << 4) + (k0 & 15);
        *(int*)(base + addr) = packed;
    }
    if (t == 0) scales[m] = scale;
}

// ---------------- kernel 2: int8 GEMM + dequant epilogue ----------------
// grid = 256 blocks (1/CU), 512 thr = 8 waves, each wave one 32x32 m-tile.
// 2-stage pipeline, raw barriers (lgkmcnt only, never vmcnt-drain): qw chunk
// sc+2 issued at top of iter sc, consumed by stage_b at end of iter sc+1
// -> 2 chunk-sets (64KB/CU) of qw always in flight.
// A frags: one coalesced 1KB wave-load each from tiled xqt (L2/L3-served).

__device__ __forceinline__ void stage_b(char* btn, int bwo,
                                        const int4& w0, const int4& w1,
                                        const int4& w2, const int4& w3) {
    const int* p0 = (const int*)&w0;
    const int* p1 = (const int*)&w1;
    const int* p2 = (const int*)&w2;
    const int* p3 = (const int*)&w3;
#pragma unroll
    for (int j = 0; j < 4; ++j) {
        const unsigned u = __builtin_amdgcn_perm((unsigned)p1[j], (unsigned)p0[j], 0x00000400u);
        const unsigned w = __builtin_amdgcn_perm((unsigned)p3[j], (unsigned)p2[j], 0x00000400u);
        const unsigned o = __builtin_amdgcn_perm(w, u, 0x05040100u);
        *(unsigned*)(btn + bwo + j * 272) = o;
    }
}

__global__ __launch_bounds__(512) void awq_gemm(const signed char* __restrict__ xqt,
                                                const float* __restrict__ scales,
                                                const int* __restrict__ qw,
                                                const float* __restrict__ wscale,
                                                const float* __restrict__ bias,
                                                float* __restrict__ out) {
    __shared__ __align__(16) char btile[2][32 * 272];
    const int t = threadIdx.x;
    const int lane = t & 63;
    const int wave = t >> 6;
    const int n0 = blockIdx.x * 32;

    const int sa = t & 7;                  // n-group
    const int sr = t >> 3;                 // k-row group
    const int* qbase = qw + (size_t)(4 * sr) * N_ + n0 + 4 * sa;

    // tiled A base: wave's m-tile (256KB each), this lane's 16B slot
    const signed char* xqb = xqt + ((size_t)wave << 18) + lane * 16;

    const int bro = (lane & 31) * 272 + (lane >> 5) * 16;
    const int bwo = (4 * sa) * 272 + 4 * sr;

    v16i acc = {};
    v4i aF[8];
    int4 sA[4], sB[4];

    auto loadq = [&](int4* dst, int chunk) {
        const int4* q = (const int4*)(qbase + (size_t)chunk * 256 * N_);
        dst[0] = q[0];
        dst[1] = q[N_ / 4];
        dst[2] = q[2 * (N_ / 4)];
        dst[3] = q[3 * (N_ / 4)];
    };

    // prologue: sA <- chunk0, sB <- chunk1, aF <- chunk0, stage buf0
    loadq(sA, 0);
    loadq(sB, 1);
#pragma unroll
    for (int ks = 0; ks < 8; ++ks) aF[ks] = *(const v4i*)(xqb + ks * 1024);
    stage_b(&btile[0][0], bwo, sA[0], sA[1], sA[2], sA[3]);
    asm volatile("s_waitcnt lgkmcnt(0)" ::: "memory");
    __builtin_amdgcn_s_barrier();
    __builtin_amdgcn_sched_barrier(0);

    for (int sc = 0; sc < 32; sc += 2) {
        {   // even: compute chunk sc (buf0); stage sc+1 (sB) -> buf1; issue sc+2 -> sA
            const int c2 = (sc + 2 < 32) ? sc + 2 : 31;
            loadq(sA, c2);
            const int an = (sc + 1 < 32) ? sc + 1 : 31;
            const char* btc = &btile[0][0];
#pragma unroll
            for (int ks = 0; ks < 8; ++ks) {
                const v4i bf = *(const v4i*)(btc + bro + ks * 32);
                acc = __builtin_amdgcn_mfma_i32_32x32x32_i8(aF[ks], bf, acc, 0, 0, 0);
                aF[ks] = *(const v4i*)(xqb + an * 8192 + ks * 1024);
            }
            stage_b(&btile[1][0], bwo, sB[0], sB[1], sB[2], sB[3]);
            asm volatile("s_waitcnt lgkmcnt(0)" ::: "memory");
            __builtin_amdgcn_s_barrier();
            __builtin_amdgcn_sched_barrier(0);
        }
        {   // odd: compute chunk sc+1 (buf1); stage sc+2 (sA) -> buf0; issue sc+3 -> sB
            const int c3 = (sc + 3 < 32) ? sc + 3 : 31;
            loadq(sB, c3);
            const int an = (sc + 2 < 32) ? sc + 2 : 31;
            const char* btc = &btile[1][0];
#pragma unroll
            for (int ks = 0; ks < 8; ++ks) {
                const v4i bf = *(const v4i*)(btc + bro + ks * 32);
                acc = __builtin_amdgcn_mfma_i32_32x32x32_i8(aF[ks], bf, acc, 0, 0, 0);
                aF[ks] = *(const v4i*)(xqb + an * 8192 + ks * 1024);
            }
            stage_b(&btile[0][0], bwo, sA[0], sA[1], sA[2], sA[3]);
            asm volatile("s_waitcnt lgkmcnt(0)" ::: "memory");
            __builtin_amdgcn_s_barrier();
            __builtin_amdgcn_sched_barrier(0);
        }
    }

    // epilogue: dequant. C/D layout: col=lane&31, row=(g&3)+8*(g>>2)+4*(lane>>5)
    const int n = n0 + (lane & 31);
    const float wn = wscale[n];
    const float bn = bias[n];
    const int mb = wave * 32 + 4 * (lane >> 5);
#pragma unroll
    for (int g = 0; g < 16; ++g) {
        const int m = mb + (g & 3) + 8 * (g >> 2);
        out[(size_t)m * N_ + n] = ((float)acc[g] * scales[m]) * wn + bn;
    }
}

extern "C" void kernel_launch(void* const* d_in, const int* in_sizes, int n_in,
                              void* d_out, int out_size, void* d_ws, size_t ws_size,
                              hipStream_t stream) {
    const float* x    = (const float*)d_in[0];
    const int*   qw   = (const int*)d_in[1];
    const float* wsc  = (const float*)d_in[2];
    const float* bias = (const float*)d_in[3];
    float* out = (float*)d_out;

    signed char* xqbuf  = (signed char*)d_ws;                      // 2 MB, tiled
    float*       scales = (float*)((char*)d_ws + (size_t)M_ * K_); // 1 KB

    awq_quant<<<M_, 256, 0, stream>>>(x, xqbuf, scales);
    awq_gemm<<<N_ / 32, 512, 0, stream>>>(xqbuf, scales, qw, wsc, bias, out);
}